// Round 1
// baseline (402.086 us; speedup 1.0000x reference)
//
#include <hip/hip_runtime.h>

#define KDIM 256
#define DWIN 20
#define NOBS 8192
#define TAU  20
#define TROWS (NOBS - TAU)          // 8172
#define BM 16
#define NBLK ((TROWS + BM - 1) / BM) // 511

// lam[i,k] = beta0[k] + sum_{a,b} obs[i+a,b] * beta1[k,b,a]
// thread k = column; block = BM rows; beta1 row streamed per-lane,
// obs column values are wave-uniform -> scalar loads.
__global__ __launch_bounds__(KDIM, 2)
void poisson_lam_kernel(const float* __restrict__ obs,
                        const float* __restrict__ beta0,
                        const float* __restrict__ beta1,
                        float* __restrict__ out,       // out[0]=loglik, out[1..]=lam
                        double* __restrict__ partials)
{
    const int k  = threadIdx.x;
    const int i0 = blockIdx.x * BM;
    const int nr = min(BM, TROWS - i0);
    const int smax = nr + DWIN - 1;        // rows of obs actually needed

    float acc[BM];
#pragma unroll
    for (int r = 0; r < BM; ++r) acc[r] = 0.f;

    const float* __restrict__ b1k = beta1 + (size_t)k * (KDIM * DWIN);

    for (int b = 0; b < KDIM; ++b) {
        // per-lane: 20 contiguous floats beta1[k][b][0..19] (80B, 16B-aligned)
        float br[DWIN];
        const float4* q = (const float4*)(b1k + b * DWIN);
#pragma unroll
        for (int v = 0; v < DWIN / 4; ++v) {
            float4 t = q[v];
            br[4*v+0] = t.x; br[4*v+1] = t.y; br[4*v+2] = t.z; br[4*v+3] = t.w;
        }
        // wave-uniform obs column b, rows i0 .. i0+smax-1
        float w[BM + DWIN - 1];
#pragma unroll
        for (int s = 0; s < BM + DWIN - 1; ++s)
            w[s] = (s < smax) ? obs[(size_t)(i0 + s) * KDIM + b] : 0.f;
        // register-resident 16x20 FMA block
#pragma unroll
        for (int r = 0; r < BM; ++r) {
#pragma unroll
            for (int a = 0; a < DWIN; ++a)
                acc[r] = fmaf(w[r + a], br[a], acc[r]);
        }
    }

    // epilogue: add beta0, write lam, accumulate loglik partial
    const float b0 = beta0[k];
    double part = 0.0;
    for (int r = 0; r < nr; ++r) {
        float lam = acc[r] + b0;
        out[1 + (size_t)(i0 + r) * KDIM + k] = lam;
        float o = obs[(size_t)(i0 + r + TAU) * KDIM + k];
        part += (double)(o * logf(lam) - lam);
    }

    __shared__ double sred[KDIM];
    sred[k] = part;
    __syncthreads();
    for (int off = KDIM / 2; off > 0; off >>= 1) {
        if (k < off) sred[k] += sred[k + off];
        __syncthreads();
    }
    if (k == 0) partials[blockIdx.x] = sred[0];
}

__global__ void poisson_reduce_kernel(const double* __restrict__ partials,
                                      float* __restrict__ out)
{
    __shared__ double sred[256];
    double v = 0.0;
    for (int i = threadIdx.x; i < NBLK; i += 256) v += partials[i];
    sred[threadIdx.x] = v;
    __syncthreads();
    for (int off = 128; off > 0; off >>= 1) {
        if (threadIdx.x < off) sred[threadIdx.x] += sred[threadIdx.x + off];
        __syncthreads();
    }
    if (threadIdx.x == 0) out[0] = (float)sred[0];
}

extern "C" void kernel_launch(void* const* d_in, const int* in_sizes, int n_in,
                              void* d_out, int out_size, void* d_ws, size_t ws_size,
                              hipStream_t stream)
{
    const float* obs   = (const float*)d_in[0];
    const float* beta0 = (const float*)d_in[1];
    const float* beta1 = (const float*)d_in[2];
    float* out = (float*)d_out;
    double* partials = (double*)d_ws;   // NBLK doubles = 4088 B

    hipLaunchKernelGGL(poisson_lam_kernel, dim3(NBLK), dim3(KDIM), 0, stream,
                       obs, beta0, beta1, out, partials);
    hipLaunchKernelGGL(poisson_reduce_kernel, dim3(1), dim3(256), 0, stream,
                       partials, out);
}

// Round 2
// 132.228 us; speedup vs baseline: 3.0409x; 3.0409x over previous
//
#include <hip/hip_runtime.h>

#define KDIM 256
#define DWIN 20
#define NOBS 8192
#define TAU  20
#define TROWS (NOBS - TAU)          // 8172
#define KTOT  (DWIN * KDIM)         // 5120
#define KSTEPS (KTOT / 32)          // 160
#define NTILES (KDIM / 16)          // 16

#define BM 32
#define NBLK ((TROWS + BM - 1) / BM)   // 256

typedef __bf16 bf16x8 __attribute__((ext_vector_type(8)));
typedef float  f32x4  __attribute__((ext_vector_type(4)));

// ws layout (bytes):
#define WS_OBS   0u
#define WS_BF    (NOBS * KDIM * 2u)                           // 4,194,304
#define WS_PART  (WS_BF + (KSTEPS * NTILES * 64u * 8u * 2u))  // 6,815,744
#define WS_NEED  (WS_PART + 8192u)

__device__ __forceinline__ unsigned short f2bf(float f) {
    unsigned int u = __float_as_uint(f);
    unsigned int r = (u + 0x7fffu + ((u >> 16) & 1u)) >> 16;   // RN-even
    return (unsigned short)r;
}

// ---- prep: obs fp32 -> bf16 (same flat layout) ----
__global__ void prep_obs_kernel(const float* __restrict__ obs,
                                unsigned short* __restrict__ ob)
{
    int i = blockIdx.x * 256 + threadIdx.x;          // [0, 524288)
    float4 v = ((const float4*)obs)[i];
    ushort4 r;
    r.x = f2bf(v.x); r.y = f2bf(v.y); r.z = f2bf(v.z); r.w = f2bf(v.w);
    ((ushort4*)ob)[i] = r;
}

// ---- prep: beta1 -> fragment-major B ----
// Bfrag[((ks*16 + nt)*64 + lane)*8 + j] = bf16(B[k][n]),
//   k = ks*32 + (lane>>4)*8 + j,  n = nt*16 + (lane&15),
//   B[k][n] = beta1[n][b][a], a = k>>8, b = k&255
__global__ void prep_bfrag_kernel(const float* __restrict__ beta1,
                                  unsigned short* __restrict__ Bf)
{
    int idx  = blockIdx.x * 256 + threadIdx.x;       // [0, 1310720)
    int j    = idx & 7;
    int lane = (idx >> 3) & 63;
    int nt   = (idx >> 9) & 15;
    int ks   = idx >> 13;
    int k = ks * 32 + (lane >> 4) * 8 + j;
    int n = nt * 16 + (lane & 15);
    int a = k >> 8;
    int b = k & 255;
    Bf[idx] = f2bf(beta1[(size_t)n * KTOT + b * DWIN + a]);
}

// ---- main GEMM: wave = 32 rows x 64 cols, block = 32 rows x 256 cols ----
__global__ __launch_bounds__(256)
void gemm_kernel(const float* __restrict__ obs,
                 const float* __restrict__ beta0,
                 const unsigned short* __restrict__ obsb,
                 const unsigned short* __restrict__ Bf,
                 float* __restrict__ out,
                 double* __restrict__ partials)
{
    const int tid  = threadIdx.x;
    const int lane = tid & 63;
    const int wave = tid >> 6;
    const int g = lane >> 4;       // 16-lane group
    const int q = lane & 15;
    const int i0 = blockIdx.x * BM;

    // clamp rows so loads stay in-bounds; invalid rows are never written
    const int r0 = min(i0 + q,      TROWS - 1);
    const int r1 = min(i0 + 16 + q, TROWS - 1);

    const unsigned short* ap0 = obsb + (size_t)r0 * KDIM + 8 * g;
    const unsigned short* ap1 = obsb + (size_t)r1 * KDIM + 8 * g;
    const unsigned short* bp0 = Bf + (size_t)(wave * 4) * 512 + (size_t)lane * 8;

    f32x4 acc[2][4];
#pragma unroll
    for (int m = 0; m < 2; ++m)
#pragma unroll
        for (int t = 0; t < 4; ++t)
            acc[m][t] = (f32x4){0.f, 0.f, 0.f, 0.f};

#pragma unroll 2
    for (int ks = 0; ks < KSTEPS; ++ks) {
        bf16x8 a0 = *(const bf16x8*)(ap0 + ks * 32);
        bf16x8 a1 = *(const bf16x8*)(ap1 + ks * 32);
        const unsigned short* bp = bp0 + (size_t)ks * (NTILES * 512);
#pragma unroll
        for (int t = 0; t < 4; ++t) {
            bf16x8 b = *(const bf16x8*)(bp + t * 512);
            acc[0][t] = __builtin_amdgcn_mfma_f32_16x16x32_bf16(a0, b, acc[0][t], 0, 0, 0);
            acc[1][t] = __builtin_amdgcn_mfma_f32_16x16x32_bf16(a1, b, acc[1][t], 0, 0, 0);
        }
    }

    // epilogue: lam = acc + beta0, write, loglik partial
    double part = 0.0;
#pragma unroll
    for (int t = 0; t < 4; ++t) {
        const int col = wave * 64 + t * 16 + q;
        const float b0v = beta0[col];
#pragma unroll
        for (int m = 0; m < 2; ++m) {
#pragma unroll
            for (int r = 0; r < 4; ++r) {
                const int row = i0 + m * 16 + 4 * g + r;   // C/D: row=(lane>>4)*4+reg
                if (row < TROWS) {
                    float lam = acc[m][t][r] + b0v;
                    out[1 + (size_t)row * KDIM + col] = lam;
                    float o = obs[(size_t)(row + TAU) * KDIM + col];
                    part += (double)o * (double)__logf(lam) - (double)lam;
                }
            }
        }
    }

    __shared__ double sred[256];
    sred[tid] = part;
    __syncthreads();
    for (int off = 128; off > 0; off >>= 1) {
        if (tid < off) sred[tid] += sred[tid + off];
        __syncthreads();
    }
    if (tid == 0) partials[blockIdx.x] = sred[0];
}

__global__ void reduce_final_kernel(const double* __restrict__ partials,
                                    float* __restrict__ out, int n)
{
    __shared__ double sred[256];
    double v = 0.0;
    for (int i = threadIdx.x; i < n; i += 256) v += partials[i];
    sred[threadIdx.x] = v;
    __syncthreads();
    for (int off = 128; off > 0; off >>= 1) {
        if (threadIdx.x < off) sred[threadIdx.x] += sred[threadIdx.x + off];
        __syncthreads();
    }
    if (threadIdx.x == 0) out[0] = (float)sred[0];
}

// ================= fallback fp32 path (R1, proven) =================
#define BM_OLD 16
#define NBLK_OLD ((TROWS + BM_OLD - 1) / BM_OLD)   // 511

__global__ __launch_bounds__(KDIM, 2)
void old_lam_kernel(const float* __restrict__ obs,
                    const float* __restrict__ beta0,
                    const float* __restrict__ beta1,
                    float* __restrict__ out,
                    double* __restrict__ partials)
{
    const int k  = threadIdx.x;
    const int i0 = blockIdx.x * BM_OLD;
    const int nr = min(BM_OLD, TROWS - i0);
    const int smax = nr + DWIN - 1;

    float acc[BM_OLD];
#pragma unroll
    for (int r = 0; r < BM_OLD; ++r) acc[r] = 0.f;

    const float* __restrict__ b1k = beta1 + (size_t)k * (KDIM * DWIN);

    for (int b = 0; b < KDIM; ++b) {
        float br[DWIN];
        const float4* qd = (const float4*)(b1k + b * DWIN);
#pragma unroll
        for (int v = 0; v < DWIN / 4; ++v) {
            float4 t = qd[v];
            br[4*v+0] = t.x; br[4*v+1] = t.y; br[4*v+2] = t.z; br[4*v+3] = t.w;
        }
        float w[BM_OLD + DWIN - 1];
#pragma unroll
        for (int s = 0; s < BM_OLD + DWIN - 1; ++s)
            w[s] = (s < smax) ? obs[(size_t)(i0 + s) * KDIM + b] : 0.f;
#pragma unroll
        for (int r = 0; r < BM_OLD; ++r)
#pragma unroll
            for (int a = 0; a < DWIN; ++a)
                acc[r] = fmaf(w[r + a], br[a], acc[r]);
    }

    const float b0 = beta0[k];
    double part = 0.0;
    for (int r = 0; r < nr; ++r) {
        float lam = acc[r] + b0;
        out[1 + (size_t)(i0 + r) * KDIM + k] = lam;
        float o = obs[(size_t)(i0 + r + TAU) * KDIM + k];
        part += (double)(o * logf(lam) - lam);
    }

    __shared__ double sred[KDIM];
    sred[k] = part;
    __syncthreads();
    for (int off = KDIM / 2; off > 0; off >>= 1) {
        if (k < off) sred[k] += sred[k + off];
        __syncthreads();
    }
    if (k == 0) partials[blockIdx.x] = sred[0];
}
// ===================================================================

extern "C" void kernel_launch(void* const* d_in, const int* in_sizes, int n_in,
                              void* d_out, int out_size, void* d_ws, size_t ws_size,
                              hipStream_t stream)
{
    const float* obs   = (const float*)d_in[0];
    const float* beta0 = (const float*)d_in[1];
    const float* beta1 = (const float*)d_in[2];
    float* out = (float*)d_out;

    if (ws_size >= (size_t)WS_NEED) {
        unsigned short* obsb = (unsigned short*)((char*)d_ws + WS_OBS);
        unsigned short* Bf   = (unsigned short*)((char*)d_ws + WS_BF);
        double* partials     = (double*)((char*)d_ws + WS_PART);

        hipLaunchKernelGGL(prep_obs_kernel,   dim3(2048), dim3(256), 0, stream, obs, obsb);
        hipLaunchKernelGGL(prep_bfrag_kernel, dim3(5120), dim3(256), 0, stream, beta1, Bf);
        hipLaunchKernelGGL(gemm_kernel, dim3(NBLK), dim3(256), 0, stream,
                           obs, beta0, obsb, Bf, out, partials);
        hipLaunchKernelGGL(reduce_final_kernel, dim3(1), dim3(256), 0, stream,
                           partials, out, NBLK);
    } else {
        double* partials = (double*)d_ws;
        hipLaunchKernelGGL(old_lam_kernel, dim3(NBLK_OLD), dim3(KDIM), 0, stream,
                           obs, beta0, beta1, out, partials);
        hipLaunchKernelGGL(reduce_final_kernel, dim3(1), dim3(256), 0, stream,
                           partials, out, NBLK_OLD);
    }
}

// Round 3
// 68.611 us; speedup vs baseline: 5.8604x; 1.9272x over previous
//
#include <hip/hip_runtime.h>

#define KDIM 256
#define DWIN 20
#define NOBS 8192
#define TAU  20
#define TROWS (NOBS - TAU)          // 8172
#define KTOT  (DWIN * KDIM)         // 5120
#define KSTEPS (KTOT / 32)          // 160
#define NTILES (KDIM / 16)          // 16

#define BM 64
#define NBLK_M ((TROWS + BM - 1) / BM)   // 128
#define NBLK   (NBLK_M * 4)              // 512

#define AROWS 83                     // 64 + DWIN - 1
#define APAD  280                    // 256 + 24 pad (560B rowstride = 35*16B)

typedef __bf16 bf16x8 __attribute__((ext_vector_type(8)));
typedef float  f32x4  __attribute__((ext_vector_type(4)));

// ws layout (bytes):
#define WS_BF    0u
#define WS_PART  (KSTEPS * NTILES * 64u * 8u * 2u)   // 2,621,440
#define WS_NEED  (WS_PART + NBLK * 8u)

__device__ __forceinline__ unsigned short f2bf(float f) {
    unsigned int u = __float_as_uint(f);
    unsigned int r = (u + 0x7fffu + ((u >> 16) & 1u)) >> 16;   // RN-even
    return (unsigned short)r;
}

// ---- prep: beta1 -> fragment-major B (verified R2) ----
// Bf[((ks*16 + nt)*64 + lane)*8 + j] = bf16(B[k][n]),
//   k = ks*32 + (lane>>4)*8 + j,  n = nt*16 + (lane&15),
//   B[k][n] = beta1[n][b][a], a = k>>8, b = k&255
__global__ void prep_bfrag_kernel(const float* __restrict__ beta1,
                                  unsigned short* __restrict__ Bf)
{
    int idx  = blockIdx.x * 256 + threadIdx.x;       // [0, 1310720)
    int j    = idx & 7;
    int lane = (idx >> 3) & 63;
    int nt   = (idx >> 9) & 15;
    int ks   = idx >> 13;
    int k = ks * 32 + (lane >> 4) * 8 + j;
    int n = nt * 16 + (lane & 15);
    int a = k >> 8;
    int b = k & 255;
    Bf[idx] = f2bf(beta1[(size_t)n * KTOT + b * DWIN + a]);
}

// ---- main GEMM: block = 64 rows x 64 cols, 4 waves (each 16r x 64c) ----
__global__ __launch_bounds__(256, 2)
void gemm_kernel(const float* __restrict__ obs,
                 const float* __restrict__ beta0,
                 const unsigned short* __restrict__ Bf,
                 float* __restrict__ out,
                 double* __restrict__ partials)
{
    const int tid  = threadIdx.x;
    const int lane = tid & 63;
    const int wave = tid >> 6;     // 0..3, owns rows [wave*16, wave*16+16)
    const int g = lane >> 4;       // 16-lane group
    const int q = lane & 15;
    const int nb = blockIdx.x & 3;         // 64-col panel
    const int mb = blockIdx.x >> 2;
    const int i0 = mb * BM;

    __shared__ unsigned short ldsA[AROWS * APAD];   // 46,480 B
    __shared__ unsigned short ldsB[2][2][2048];     // 16,384 B (dbuf x ks-half x 4KB)
    __shared__ double sred[4];

    // --- stage A panel: obs rows i0..i0+82 (clamped), fused fp32->bf16 ---
    for (int idx = tid; idx < AROWS * 64; idx += 256) {
        int row = idx >> 6, c4 = idx & 63;
        int grow = min(i0 + row, NOBS - 1);
        float4 v = ((const float4*)obs)[(size_t)grow * 64 + c4];
        ushort4 r;
        r.x = f2bf(v.x); r.y = f2bf(v.y); r.z = f2bf(v.z); r.w = f2bf(v.w);
        *(ushort4*)&ldsA[row * APAD + c4 * 4] = r;
    }

    // --- B stage: 8KB per iter (2 K-steps), 2 x 16B per thread ---
    const unsigned short* bsrc0 = Bf + (size_t)nb * 4 * 512 + tid * 8;
#define STAGE_B(it, p)                                                          \
    {                                                                           \
        _Pragma("unroll")                                                       \
        for (int h = 0; h < 2; ++h) {                                           \
            const unsigned short* src = bsrc0 + (size_t)(2*(it) + h) * (16*512);\
            __builtin_amdgcn_global_load_lds(                                   \
                (const __attribute__((address_space(1))) unsigned int*)src,     \
                (__attribute__((address_space(3))) unsigned int*)&ldsB[p][h][tid*8], \
                16, 0, 0);                                                      \
        }                                                                       \
    }

    STAGE_B(0, 0)
    __syncthreads();   // drains vmcnt (B stage) + lgkm (A ds_writes)

    f32x4 acc[4];
#pragma unroll
    for (int t = 0; t < 4; ++t) acc[t] = (f32x4){0.f, 0.f, 0.f, 0.f};

#pragma unroll 1
    for (int it = 0; it < KSTEPS / 2; ++it) {
        const int p = it & 1;
        if (it + 1 < KSTEPS / 2) STAGE_B(it + 1, p ^ 1)
#pragma unroll
        for (int h = 0; h < 2; ++h) {
            const int ks = 2 * it + h;
            const int arow = wave * 16 + q + (ks >> 3);
            bf16x8 a = *(const bf16x8*)&ldsA[arow * APAD + ((ks & 7) * 32 + 8 * g)];
#pragma unroll
            for (int t = 0; t < 4; ++t) {
                bf16x8 b = *(const bf16x8*)&ldsB[p][h][t * 512 + lane * 8];
                acc[t] = __builtin_amdgcn_mfma_f32_16x16x32_bf16(a, b, acc[t], 0, 0, 0);
            }
        }
        __syncthreads();   // dbuf handshake (vmcnt+lgkm drained by compiler)
    }

    // --- epilogue: lam = acc + beta0, write, loglik partial ---
    double part = 0.0;
#pragma unroll
    for (int t = 0; t < 4; ++t) {
        const int col = nb * 64 + t * 16 + q;
        const float b0v = beta0[col];
#pragma unroll
        for (int r = 0; r < 4; ++r) {
            const int row = i0 + wave * 16 + 4 * g + r;   // C/D: row=(lane>>4)*4+reg
            if (row < TROWS) {
                float lam = acc[t][r] + b0v;
                out[1 + (size_t)row * KDIM + col] = lam;
                float o = obs[(size_t)(row + TAU) * KDIM + col];
                part += (double)o * (double)__logf(lam) - (double)lam;
            }
        }
    }

    // wave shuffle-reduce (double), then 4-entry LDS
#pragma unroll
    for (int off = 32; off > 0; off >>= 1) part += __shfl_down(part, off, 64);
    if (lane == 0) sred[wave] = part;
    __syncthreads();
    if (tid == 0) partials[blockIdx.x] = sred[0] + sred[1] + sred[2] + sred[3];
}

__global__ void reduce_final_kernel(const double* __restrict__ partials,
                                    float* __restrict__ out, int n)
{
    __shared__ double sr[256];
    double v = 0.0;
    for (int i = threadIdx.x; i < n; i += 256) v += partials[i];
    sr[threadIdx.x] = v;
    __syncthreads();
    for (int off = 128; off > 0; off >>= 1) {
        if (threadIdx.x < off) sr[threadIdx.x] += sr[threadIdx.x + off];
        __syncthreads();
    }
    if (threadIdx.x == 0) out[0] = (float)sr[0];
}

// ================= fallback fp32 path (R1, proven) =================
#define BM_OLD 16
#define NBLK_OLD ((TROWS + BM_OLD - 1) / BM_OLD)   // 511

__global__ __launch_bounds__(KDIM, 2)
void old_lam_kernel(const float* __restrict__ obs,
                    const float* __restrict__ beta0,
                    const float* __restrict__ beta1,
                    float* __restrict__ out,
                    double* __restrict__ partials)
{
    const int k  = threadIdx.x;
    const int i0 = blockIdx.x * BM_OLD;
    const int nr = min(BM_OLD, TROWS - i0);
    const int smax = nr + DWIN - 1;

    float acc[BM_OLD];
#pragma unroll
    for (int r = 0; r < BM_OLD; ++r) acc[r] = 0.f;

    const float* __restrict__ b1k = beta1 + (size_t)k * (KDIM * DWIN);

    for (int b = 0; b < KDIM; ++b) {
        float br[DWIN];
        const float4* qd = (const float4*)(b1k + b * DWIN);
#pragma unroll
        for (int v = 0; v < DWIN / 4; ++v) {
            float4 t = qd[v];
            br[4*v+0] = t.x; br[4*v+1] = t.y; br[4*v+2] = t.z; br[4*v+3] = t.w;
        }
        float w[BM_OLD + DWIN - 1];
#pragma unroll
        for (int s = 0; s < BM_OLD + DWIN - 1; ++s)
            w[s] = (s < smax) ? obs[(size_t)(i0 + s) * KDIM + b] : 0.f;
#pragma unroll
        for (int r = 0; r < BM_OLD; ++r)
#pragma unroll
            for (int a = 0; a < DWIN; ++a)
                acc[r] = fmaf(w[r + a], br[a], acc[r]);
    }

    const float b0 = beta0[k];
    double part = 0.0;
    for (int r = 0; r < nr; ++r) {
        float lam = acc[r] + b0;
        out[1 + (size_t)(i0 + r) * KDIM + k] = lam;
        float o = obs[(size_t)(i0 + r + TAU) * KDIM + k];
        part += (double)(o * logf(lam) - lam);
    }

    __shared__ double sred2[KDIM];
    sred2[k] = part;
    __syncthreads();
    for (int off = KDIM / 2; off > 0; off >>= 1) {
        if (k < off) sred2[k] += sred2[k + off];
        __syncthreads();
    }
    if (k == 0) partials[blockIdx.x] = sred2[0];
}
// ===================================================================

extern "C" void kernel_launch(void* const* d_in, const int* in_sizes, int n_in,
                              void* d_out, int out_size, void* d_ws, size_t ws_size,
                              hipStream_t stream)
{
    const float* obs   = (const float*)d_in[0];
    const float* beta0 = (const float*)d_in[1];
    const float* beta1 = (const float*)d_in[2];
    float* out = (float*)d_out;

    if (ws_size >= (size_t)WS_NEED) {
        unsigned short* Bf = (unsigned short*)((char*)d_ws + WS_BF);
        double* partials   = (double*)((char*)d_ws + WS_PART);

        hipLaunchKernelGGL(prep_bfrag_kernel, dim3(5120), dim3(256), 0, stream, beta1, Bf);
        hipLaunchKernelGGL(gemm_kernel, dim3(NBLK), dim3(256), 0, stream,
                           obs, beta0, Bf, out, partials);
        hipLaunchKernelGGL(reduce_final_kernel, dim3(1), dim3(256), 0, stream,
                           partials, out, NBLK);
    } else {
        double* partials = (double*)d_ws;
        hipLaunchKernelGGL(old_lam_kernel, dim3(NBLK_OLD), dim3(KDIM), 0, stream,
                           obs, beta0, beta1, out, partials);
        hipLaunchKernelGGL(reduce_final_kernel, dim3(1), dim3(256), 0, stream,
                           partials, out, NBLK_OLD);
    }
}

// Round 4
// 41.035 us; speedup vs baseline: 9.7985x; 1.6720x over previous
//
#include <hip/hip_runtime.h>

#define KDIM 256
#define DWIN 20
#define NOBS 8192
#define TAU  20
#define TROWS (NOBS - TAU)          // 8172
#define KTOT  (DWIN * KDIM)         // 5120
#define KSTEPS (KTOT / 32)          // 160
#define NTILES (KDIM / 16)          // 16

#define BM 64
#define NBLK_M ((TROWS + BM - 1) / BM)   // 128
#define NBLK   (NBLK_M * 4)              // 512

#define AROWS 83                     // 64 + DWIN - 1
#define APAD  280                    // 560B row stride

// dynamic LDS layout (bytes)
#define A_BYTES   (AROWS * APAD * 2)        // 46480
#define B_OFF     46592                      // 128B-aligned
#define RING_STRIDE 16384                    // 4 waves x 4KB
#define SRED_OFF  (B_OFF + 2 * RING_STRIDE) // 79360
#define DYN_TOTAL 79424

typedef __bf16 bf16x8 __attribute__((ext_vector_type(8)));
typedef float  f32x4  __attribute__((ext_vector_type(4)));

// ws layout (bytes):
#define WS_BF    0u
#define WS_PART  (KSTEPS * NTILES * 64u * 8u * 2u)   // 2,621,440
#define WS_NEED  (WS_PART + NBLK * 8u)

__device__ __forceinline__ unsigned short f2bf(float f) {
    unsigned int u = __float_as_uint(f);
    unsigned int r = (u + 0x7fffu + ((u >> 16) & 1u)) >> 16;   // RN-even
    return (unsigned short)r;
}

// ---- prep: beta1 -> fragment-major B (verified R2/R3) ----
// Bf[((ks*16 + nt)*64 + lane)*8 + j] = bf16(B[k][n]),
//   k = ks*32 + (lane>>4)*8 + j,  n = nt*16 + (lane&15),
//   B[k][n] = beta1[n][b][a], a = k>>8, b = k&255
__global__ void prep_bfrag_kernel(const float* __restrict__ beta1,
                                  unsigned short* __restrict__ Bf)
{
    int idx  = blockIdx.x * 256 + threadIdx.x;       // [0, 1310720)
    int j    = idx & 7;
    int lane = (idx >> 3) & 63;
    int nt   = (idx >> 9) & 15;
    int ks   = idx >> 13;
    int k = ks * 32 + (lane >> 4) * 8 + j;
    int n = nt * 16 + (lane & 15);
    int a = k >> 8;
    int b = k & 255;
    Bf[idx] = f2bf(beta1[(size_t)n * KTOT + b * DWIN + a]);
}

extern __shared__ char dynlds[];

// ---- main GEMM: block 64x64 output, 4 waves K-split, barrier-free loop ----
__global__ __launch_bounds__(256, 2)
void gemm_kernel(const float* __restrict__ obs,
                 const float* __restrict__ beta0,
                 const unsigned short* __restrict__ Bf,
                 float* __restrict__ out,
                 double* __restrict__ partials)
{
    const int tid  = threadIdx.x;
    const int lane = tid & 63;
    const int w    = tid >> 6;     // wave id: K-quarter owner
    const int g = lane >> 4;
    const int q = lane & 15;
    const int nb = blockIdx.x & 3;
    const int mb = blockIdx.x >> 2;
    const int i0 = mb * BM;

    unsigned short* ldsA = (unsigned short*)dynlds;

    // --- stage A panel: rows i0..i0+82 (clamped), fused fp32->bf16 ---
    for (int idx = tid; idx < AROWS * 64; idx += 256) {
        int row = idx >> 6, c4 = idx & 63;
        int grow = min(i0 + row, NOBS - 1);
        float4 v = ((const float4*)obs)[(size_t)grow * 64 + c4];
        ushort4 r;
        r.x = f2bf(v.x); r.y = f2bf(v.y); r.z = f2bf(v.z); r.w = f2bf(v.w);
        *(ushort4*)&ldsA[row * APAD + c4 * 4] = r;
    }

    // wave w stages its own K32-slice `ks` into ring slot r (4KB, 4x16B/lane)
#define STAGE(ks, rr)                                                            \
    {                                                                            \
        const char* _src = (const char*)Bf + ((size_t)((ks) * 16 + 4 * nb)) * 1024 + lane * 16; \
        char* _dst = dynlds + B_OFF + (rr) * RING_STRIDE + w * 4096 + lane * 16; \
        _Pragma("unroll")                                                        \
        for (int _i = 0; _i < 4; ++_i)                                           \
            __builtin_amdgcn_global_load_lds(                                    \
                (const __attribute__((address_space(1))) unsigned int*)(_src + _i * 1024), \
                (__attribute__((address_space(3))) unsigned int*)(_dst + _i * 1024),       \
                16, 0, 0);                                                       \
    }

    const int ks0 = 40 * w;
    STAGE(ks0, 0)
    __syncthreads();   // A ready; drains stage(0) too

    f32x4 acc[4][4];
#pragma unroll
    for (int m = 0; m < 4; ++m)
#pragma unroll
        for (int t = 0; t < 4; ++t)
            acc[m][t] = (f32x4){0.f, 0.f, 0.f, 0.f};

#define COMPUTE(s)                                                               \
    {                                                                            \
        const int _ks = ks0 + (s);                                               \
        const int _acol = ((_ks & 7) * 32 + g * 8);                              \
        const int _aro  = (_ks >> 3);                                            \
        bf16x8 _af[4];                                                           \
        _Pragma("unroll")                                                        \
        for (int m = 0; m < 4; ++m)                                              \
            _af[m] = *(const bf16x8*)&ldsA[(m * 16 + q + _aro) * APAD + _acol];  \
        const char* _bb = dynlds + B_OFF + ((s) & 1) * RING_STRIDE + w * 4096 + lane * 16; \
        _Pragma("unroll")                                                        \
        for (int t = 0; t < 4; ++t) {                                            \
            bf16x8 _b = *(const bf16x8*)(_bb + t * 1024);                        \
            _Pragma("unroll")                                                    \
            for (int m = 0; m < 4; ++m)                                          \
                acc[m][t] = __builtin_amdgcn_mfma_f32_16x16x32_bf16(_af[m], _b, acc[m][t], 0, 0, 0); \
        }                                                                        \
    }

#pragma unroll 2
    for (int s = 0; s < 39; ++s) {
        STAGE(ks0 + s + 1, (s + 1) & 1)
        asm volatile("s_waitcnt vmcnt(4)" ::: "memory");   // stage(s) landed
        COMPUTE(s)
    }
    asm volatile("s_waitcnt vmcnt(0)" ::: "memory");
    COMPUTE(39)

    // --- exchange partial C through LDS (reuse A+B region) ---
    __syncthreads();
    f32x4* pc = (f32x4*)dynlds;        // 4096 x 16B = 64KB
#pragma unroll
    for (int m = 0; m < 4; ++m)
#pragma unroll
        for (int t = 0; t < 4; ++t)
            pc[((w * 16 + m * 4 + t) << 6) + lane] = acc[m][t];
    __syncthreads();

    // wave w reduces band m=w, fused epilogue
    double part = 0.0;
#pragma unroll
    for (int t = 0; t < 4; ++t) {
        f32x4 sum = pc[((0 * 16 + w * 4 + t) << 6) + lane];
#pragma unroll
        for (int wp = 1; wp < 4; ++wp)
            sum += pc[((wp * 16 + w * 4 + t) << 6) + lane];
        const int col = nb * 64 + t * 16 + q;
        const float b0v = beta0[col];
#pragma unroll
        for (int r = 0; r < 4; ++r) {
            const int row = i0 + w * 16 + 4 * g + r;   // C/D: row=(lane>>4)*4+reg
            if (row < TROWS) {
                float lam = sum[r] + b0v;
                out[1 + (size_t)row * KDIM + col] = lam;
                float o = obs[(size_t)(row + TAU) * KDIM + col];
                part += (double)o * (double)__logf(lam) - (double)lam;
            }
        }
    }

#pragma unroll
    for (int off = 32; off > 0; off >>= 1) part += __shfl_down(part, off, 64);
    double* sred = (double*)(dynlds + SRED_OFF);
    if (lane == 0) sred[w] = part;
    __syncthreads();
    if (tid == 0) partials[blockIdx.x] = sred[0] + sred[1] + sred[2] + sred[3];
}

__global__ void reduce_final_kernel(const double* __restrict__ partials,
                                    float* __restrict__ out, int n)
{
    __shared__ double sr[256];
    double v = 0.0;
    for (int i = threadIdx.x; i < n; i += 256) v += partials[i];
    sr[threadIdx.x] = v;
    __syncthreads();
    for (int off = 128; off > 0; off >>= 1) {
        if (threadIdx.x < off) sr[threadIdx.x] += sr[threadIdx.x + off];
        __syncthreads();
    }
    if (threadIdx.x == 0) out[0] = (float)sr[0];
}

// ================= fallback fp32 path (R1, proven) =================
#define BM_OLD 16
#define NBLK_OLD ((TROWS + BM_OLD - 1) / BM_OLD)   // 511

__global__ __launch_bounds__(KDIM, 2)
void old_lam_kernel(const float* __restrict__ obs,
                    const float* __restrict__ beta0,
                    const float* __restrict__ beta1,
                    float* __restrict__ out,
                    double* __restrict__ partials)
{
    const int k  = threadIdx.x;
    const int i0 = blockIdx.x * BM_OLD;
    const int nr = min(BM_OLD, TROWS - i0);
    const int smax = nr + DWIN - 1;

    float acc[BM_OLD];
#pragma unroll
    for (int r = 0; r < BM_OLD; ++r) acc[r] = 0.f;

    const float* __restrict__ b1k = beta1 + (size_t)k * (KDIM * DWIN);

    for (int b = 0; b < KDIM; ++b) {
        float br[DWIN];
        const float4* qd = (const float4*)(b1k + b * DWIN);
#pragma unroll
        for (int v = 0; v < DWIN / 4; ++v) {
            float4 t = qd[v];
            br[4*v+0] = t.x; br[4*v+1] = t.y; br[4*v+2] = t.z; br[4*v+3] = t.w;
        }
        float wv[BM_OLD + DWIN - 1];
#pragma unroll
        for (int s = 0; s < BM_OLD + DWIN - 1; ++s)
            wv[s] = (s < smax) ? obs[(size_t)(i0 + s) * KDIM + b] : 0.f;
#pragma unroll
        for (int r = 0; r < BM_OLD; ++r)
#pragma unroll
            for (int a = 0; a < DWIN; ++a)
                acc[r] = fmaf(wv[r + a], br[a], acc[r]);
    }

    const float b0 = beta0[k];
    double part = 0.0;
    for (int r = 0; r < nr; ++r) {
        float lam = acc[r] + b0;
        out[1 + (size_t)(i0 + r) * KDIM + k] = lam;
        float o = obs[(size_t)(i0 + r + TAU) * KDIM + k];
        part += (double)(o * logf(lam) - lam);
    }

    __shared__ double sred2[KDIM];
    sred2[k] = part;
    __syncthreads();
    for (int off = KDIM / 2; off > 0; off >>= 1) {
        if (k < off) sred2[k] += sred2[k + off];
        __syncthreads();
    }
    if (k == 0) partials[blockIdx.x] = sred2[0];
}
// ===================================================================

extern "C" void kernel_launch(void* const* d_in, const int* in_sizes, int n_in,
                              void* d_out, int out_size, void* d_ws, size_t ws_size,
                              hipStream_t stream)
{
    const float* obs   = (const float*)d_in[0];
    const float* beta0 = (const float*)d_in[1];
    const float* beta1 = (const float*)d_in[2];
    float* out = (float*)d_out;

    if (ws_size >= (size_t)WS_NEED) {
        unsigned short* Bf = (unsigned short*)((char*)d_ws + WS_BF);
        double* partials   = (double*)((char*)d_ws + WS_PART);

        (void)hipFuncSetAttribute(reinterpret_cast<const void*>(gemm_kernel),
                                  hipFuncAttributeMaxDynamicSharedMemorySize,
                                  DYN_TOTAL);

        hipLaunchKernelGGL(prep_bfrag_kernel, dim3(5120), dim3(256), 0, stream, beta1, Bf);
        hipLaunchKernelGGL(gemm_kernel, dim3(NBLK), dim3(256), DYN_TOTAL, stream,
                           obs, beta0, Bf, out, partials);
        hipLaunchKernelGGL(reduce_final_kernel, dim3(1), dim3(256), 0, stream,
                           partials, out, NBLK);
    } else {
        double* partials = (double*)d_ws;
        hipLaunchKernelGGL(old_lam_kernel, dim3(NBLK_OLD), dim3(KDIM), 0, stream,
                           obs, beta0, beta1, out, partials);
        hipLaunchKernelGGL(reduce_final_kernel, dim3(1), dim3(256), 0, stream,
                           partials, out, NBLK_OLD);
    }
}